// Round 11
// baseline (496.764 us; speedup 1.0000x reference)
//
#include <hip/hip_runtime.h>

typedef __bf16 bf16x8 __attribute__((ext_vector_type(8)));
typedef __bf16 bf16x4 __attribute__((ext_vector_type(4)));
typedef float  f32x4  __attribute__((ext_vector_type(4)));
typedef float  f32x16 __attribute__((ext_vector_type(16)));
typedef unsigned u32x4 __attribute__((ext_vector_type(4)));

#define MFMA16(A, B, C) __builtin_amdgcn_mfma_f32_16x16x32_bf16(A, B, C, 0, 0, 0)
#define MFMA32(A, B, C) __builtin_amdgcn_mfma_f32_32x32x16_bf16(A, B, C, 0, 0, 0)
#define AS1 __attribute__((address_space(1)))
#define AS3 __attribute__((address_space(3)))

#if __has_builtin(__builtin_amdgcn_exp2f)
#define EXP2F(x) __builtin_amdgcn_exp2f(x)
#else
#define EXP2F(x) exp2f(x)
#endif

// pure register ops, no memory type-punning
__device__ __forceinline__ unsigned pk_bf16(float lo, float hi) {
    unsigned l = (unsigned)__builtin_bit_cast(unsigned short, (__bf16)lo);
    unsigned h = (unsigned)__builtin_bit_cast(unsigned short, (__bf16)hi);
    return l | (h << 16);
}

// ---------------- fused prep: 4x weight transpose (fp32 W -> bf16 W^T) + hidden fp32->bf16 ----------------
__global__ __launch_bounds__(256) void prep(const float* __restrict__ hs,
                                            const float* __restrict__ wq,
                                            const float* __restrict__ wk,
                                            const float* __restrict__ wv,
                                            const float* __restrict__ wo,
                                            __bf16* __restrict__ xb,
                                            __bf16* __restrict__ wqkvtb,
                                            __bf16* __restrict__ wotb) {
    __shared__ float tile[32][33];
    const int z = blockIdx.z;
    const int tx = threadIdx.x, ty = threadIdx.y;   // 32x8
    if (z == 4) {                                   // convert: 4096 blocks x 2048 floats
        const int t = ty * 32 + tx;
        size_t bid = (size_t)blockIdx.y * 64 + blockIdx.x;
        size_t base = bid * 2048 + t * 4;
        for (int c = 0; c < 2; ++c) {
            float4 v = *(const float4*)(hs + base + c * 1024);
            bf16x4 o;
            o.x = (__bf16)v.x; o.y = (__bf16)v.y; o.z = (__bf16)v.z; o.w = (__bf16)v.w;
            *(bf16x4*)(xb + base + c * 1024) = o;
        }
        return;
    }
    const float* src = (z == 0) ? wq : (z == 1) ? wk : (z == 2) ? wv : wo;
    __bf16* dst = (z < 3) ? (wqkvtb + (size_t)z * 2048 * 2048) : wotb;
    int x0 = blockIdx.x * 32, y0 = blockIdx.y * 32;
    for (int r = 0; r < 4; ++r)
        tile[ty + 8 * r][tx] = src[(size_t)(y0 + ty + 8 * r) * 2048 + x0 + tx];
    __syncthreads();
    for (int r = 0; r < 4; ++r)
        dst[(size_t)(x0 + ty + 8 * r) * 2048 + y0 + tx] = (__bf16)tile[tx][ty + 8 * r];
}

// ---------------- fused rmsrope + per-head V transpose (both consume qkvb) ----------------
__global__ __launch_bounds__(256) void rope_vt(const __bf16* __restrict__ qkv,
                                               const float* __restrict__ qw,
                                               const float* __restrict__ kw,
                                               const int* __restrict__ pos_ids,
                                               __bf16* __restrict__ qhb,
                                               __bf16* __restrict__ khb,
                                               __bf16* __restrict__ vtb) {
    __shared__ __bf16 tile[32][33];
    if (blockIdx.y < 32) {
        int u = threadIdx.x >> 6, lane = threadIdx.x & 63;
        int s = blockIdx.x * 4 + u;
        int slot = blockIdx.y;              // 0-15 = q heads, 16-31 = k heads
        bool isQ = slot < 16;
        int h = slot & 15;
        size_t base = (size_t)s * 6144 + (isQ ? 0 : 2048) + h * 128 + lane * 2;
        float x0 = (float)qkv[base], x1 = (float)qkv[base + 1];
        float ss = x0 * x0 + x1 * x1;
        for (int m = 1; m < 64; m <<= 1) ss += __shfl_xor(ss, m);
        float rr = rsqrtf(ss * (1.0f / 128.0f) + 1e-6f);
        const float* wp = isQ ? qw : kw;
        float n0 = x0 * rr * wp[lane * 2], n1 = x1 * rr * wp[lane * 2 + 1];
        float freq = EXP2F(-(float)lane * 0.2076205059004571f);   // 10000^(-lane/64)
        float ang = (float)pos_ids[s] * freq;
        float sn, cs;
        sincosf(ang, &sn, &cs);
        float o0 = n0 * cs - n1 * sn;
        float o1 = n0 * sn + n1 * cs;
        // fold (1/sqrt(128)) * log2(e) into Q so scores are in exp2 domain
        if (isQ) { o0 *= 0.12751744416196178f; o1 *= 0.12751744416196178f; }
        __bf16* dst = (isQ ? qhb : khb) + (size_t)h * 4096 * 128 + (size_t)s * 128 + lane * 2;
        dst[0] = (__bf16)o0; dst[1] = (__bf16)o1;
    } else {
        int linear = (blockIdx.y - 32) * 1024 + blockIdx.x;   // [0, 8192)
        int h = linear >> 9, rem = linear & 511;
        int s0 = (rem & 127) * 32, d0 = (rem >> 7) * 32;
        int tx = threadIdx.x & 31, ty = threadIdx.x >> 5;     // 32x8
        for (int r = 0; r < 4; ++r)
            tile[ty + 8 * r][tx] = qkv[(size_t)(s0 + ty + 8 * r) * 6144 + 4096 + h * 128 + d0 + tx];
        __syncthreads();
        for (int r = 0; r < 4; ++r)
            vtb[(size_t)h * 128 * 4096 + (size_t)(d0 + ty + 8 * r) * 4096 + s0 + tx] = tile[tx][ty + 8 * r];
    }
}

// ---------------- generic bf16 MFMA GEMM: C[M,N] = A[M,K] * Bt[N,K]^T ----------------
// R9-proven: 3-deep pipelined K-loop (T3/T4), counted vmcnt, raw s_barriers, 48 KB LDS.
template <bool F32OUT>
__global__ __launch_bounds__(256) void gemm_bt(const __bf16* __restrict__ A, int lda,
                                               const __bf16* __restrict__ Bt, int ldb,
                                               void* __restrict__ Cout, int ldc, int K) {
    __shared__ __bf16 as[3][128][32];   // unpadded: required by global_load_lds contiguity
    __shared__ __bf16 bs[3][128][32];
    const int m0 = blockIdx.x * 128, n0 = blockIdx.y * 128;
    const int t = threadIdx.x;
    const int lane = t & 63, w = t >> 6;
    const int wm = (w >> 1) * 64, wn = (w & 1) * 64;
    const int ln = lane & 15, quad = lane >> 4;
    auto as3 = (AS3 uint32_t*)&as[0][0][0];
    auto bs3 = (AS3 uint32_t*)&bs[0][0][0];
    f32x4 acc[4][4] = {};

#define G_STAGE(buf, k0)                                                             \
    for (int c = 0; c < 2; ++c) {                                                    \
        int g = c * 256 + t;                                                         \
        int row = g >> 2, kc = g & 3;                                                \
        __builtin_amdgcn_global_load_lds(                                            \
            (const AS1 uint32_t*)&A[(size_t)(m0 + row) * lda + (k0) + kc * 8],       \
            as3 + (buf) * 2048 + c * 1024 + w * 256, 16, 0, 0);                      \
        __builtin_amdgcn_global_load_lds(                                            \
            (const AS1 uint32_t*)&Bt[(size_t)(n0 + row) * ldb + (k0) + kc * 8],      \
            bs3 + (buf) * 2048 + c * 1024 + w * 256, 16, 0, 0);                      \
    }

    const int nk = K >> 5;            // K-tiles of 32 (nk >= 2 for all our calls)
    G_STAGE(0, 0)
    G_STAGE(1, 32)
    for (int kt = 0; kt < nk; ++kt) {
        const int nxt = kt + 2;
        if (nxt < nk) {
            G_STAGE(nxt % 3, nxt * 32)
            asm volatile("s_waitcnt vmcnt(8)" ::: "memory");   // tile kt landed; 2 in flight
        } else if (nxt == nk) {
            asm volatile("s_waitcnt vmcnt(4)" ::: "memory");
        } else {
            asm volatile("s_waitcnt vmcnt(0)" ::: "memory");
        }
        __builtin_amdgcn_s_barrier();
        const int b = kt % 3;
        bf16x8 af[4], bfr[4];
        for (int i = 0; i < 4; ++i) af[i] = *(const bf16x8*)&as[b][wm + i * 16 + ln][quad * 8];
        for (int j = 0; j < 4; ++j) bfr[j] = *(const bf16x8*)&bs[b][wn + j * 16 + ln][quad * 8];
        for (int i = 0; i < 4; ++i)
            for (int j = 0; j < 4; ++j)
                acc[i][j] = MFMA16(af[i], bfr[j], acc[i][j]);
        __builtin_amdgcn_s_barrier();   // reads done before anyone re-targets this slot
    }
#undef G_STAGE

    // C/D layout: col = lane&15, row = quad*4 + r   [m89/m91 verified]
    for (int i = 0; i < 4; ++i)
        for (int j = 0; j < 4; ++j)
            for (int r = 0; r < 4; ++r) {
                int row = m0 + wm + i * 16 + quad * 4 + r;
                int col = n0 + wn + j * 16 + ln;
                if (F32OUT) ((float*)Cout)[(size_t)row * ldc + col] = acc[i][j][r];
                else        ((__bf16*)Cout)[(size_t)row * ldc + col] = (__bf16)acc[i][j][r];
            }
}

// ---------------- flash attention: 32x32 MFMA, in-register softmax, gload_lds staging ----------------
// R11 = R1-R4's correctness-verified 32x32 swapped-QK^T compute (S^T = K*Q^T: lane's col is
// its own q-row; P->bf16 A-frags in-register via pk_bf16 + permlane32_swap, T12) grafted onto
// R8/R9's proven gload_lds staging skeleton.
// Pathology audit (R1-R5): the 300-466MB scratch WRITE_SIZE trigger was isolated by R5 to
// register-held global-load results (kst/vst) carried across the barrier+MFMA region. This
// kernel holds NO load results in registers (global_load_lds only) -> trigger absent.
// TRIPWIRE: if WRITE_SIZE >> 16.4MB or VGPR ~110, hypothesis is wrong -> revert to R9 flash.
// ps buffer deleted: LDS 80KB -> 66KB (still 2 blocks/CU). MFMA count halved (32 vs 64/iter).
#define SOFTMAX_PV(sac, ktv)                                                        \
    {                                                                               \
        float p[16];                                                                \
        _Pragma("unroll")                                                           \
        for (int r = 0; r < 16; ++r) { p[r] = EXP2F((sac)[r]); rs += p[r]; }        \
        unsigned a00 = pk_bf16(p[0], p[1]),  a01 = pk_bf16(p[2], p[3]);             \
        unsigned b00 = pk_bf16(p[4], p[5]),  b01 = pk_bf16(p[6], p[7]);             \
        unsigned a10 = pk_bf16(p[8], p[9]),  a11 = pk_bf16(p[10], p[11]);           \
        unsigned b10 = pk_bf16(p[12], p[13]), b11 = pk_bf16(p[14], p[15]);          \
        auto s00 = __builtin_amdgcn_permlane32_swap(a00, b00, false, false);        \
        auto s01 = __builtin_amdgcn_permlane32_swap(a01, b01, false, false);        \
        auto s10 = __builtin_amdgcn_permlane32_swap(a10, b10, false, false);        \
        auto s11 = __builtin_amdgcn_permlane32_swap(a11, b11, false, false);        \
        u32x4 w0, w1;                                                               \
        w0[0] = s00[0]; w0[1] = s01[0]; w0[2] = s00[1]; w0[3] = s01[1];             \
        w1[0] = s10[0]; w1[1] = s11[0]; w1[2] = s10[1]; w1[3] = s11[1];             \
        bf16x8 pf0 = __builtin_bit_cast(bf16x8, w0);                                \
        bf16x8 pf1 = __builtin_bit_cast(bf16x8, w1);                                \
        __builtin_amdgcn_s_setprio(1);                                              \
        _Pragma("unroll")                                                           \
        for (int dt = 0; dt < 4; ++dt) {                                            \
            int vrow = dt * 32 + q32;                                               \
            int co0 = (((ktv) * 2 + 0) << 1) | hi;                                  \
            int co1 = (((ktv) * 2 + 1) << 1) | hi;                                  \
            bf16x8 vf0 = *(const bf16x8*)(vsb + vrow * 128 + ((co0 ^ (q32 & 7)) << 4)); \
            bf16x8 vf1 = *(const bf16x8*)(vsb + vrow * 128 + ((co1 ^ (q32 & 7)) << 4)); \
            oacc[dt] = MFMA32(pf0, vf0, oacc[dt]);                                  \
            oacc[dt] = MFMA32(pf1, vf1, oacc[dt]);                                  \
        }                                                                           \
        __builtin_amdgcn_s_setprio(0);                                              \
    }

__global__ __launch_bounds__(256) void flash_attn(const __bf16* __restrict__ Q,
                                                  const __bf16* __restrict__ Kb,
                                                  const __bf16* __restrict__ Vt,
                                                  __bf16* __restrict__ ctx) {
    __shared__ __bf16 kbuf[2][64][128];   // keys x dim; phys chunk = logical ^ (row&7)
    __shared__ __bf16 vbuf[2][128][64];   // dim x keys; same involution
    __shared__ float lred[4][32];         // per-wave row-sum broadcast

    // T1: XCD-contiguous remap (verified R1-R10: FETCH 139MB -> 25MB)
    int bid = blockIdx.x + (int)gridDim.x * blockIdx.y;
    int swz = (bid & 7) * 64 + (bid >> 3);
    const int h  = swz >> 5;
    const int m0 = (swz & 31) * 128;

    const int t = threadIdx.x;
    const int lane = t & 63, w = t >> 6;
    const int q32 = lane & 31, hi = lane >> 5;
    const __bf16* Qh = Q + (size_t)h * 4096 * 128;
    const __bf16* Kh = Kb + (size_t)h * 4096 * 128;
    const __bf16* Vh = Vt + (size_t)h * 128 * 4096;

    const int kcc = (t & 15) ^ ((t >> 4) & 7);   // K/Q: 16 chunks/row of 16B
    const int vcc = (t & 7) ^ ((t >> 3) & 7);    // V: 8 chunks/row of 16B
    auto kb3 = (AS3 uint32_t*)&kbuf[0][0][0];
    auto vb3 = (AS3 uint32_t*)&vbuf[0][0][0];
    const char* kbase = (const char*)&kbuf[0][0][0];
    const char* vbase = (const char*)&vbuf[0][0][0];

    // ---- stage Q through kbuf[0]; B-frag: lane holds Q[q=w*32+q32][d = dc*16 + hi*8 + 0..7] ----
    bf16x8 qf[8];
    for (int half = 0; half < 2; ++half) {
        for (int i = 0; i < 4; ++i) {
            int row = (t >> 4) + i * 16;
            *(uint4*)&kbuf[0][row][(t & 15) * 8] =
                *(const uint4*)&Qh[(size_t)(m0 + half * 64 + row) * 128 + kcc * 8];
        }
        __syncthreads();
        if ((w >> 1) == half) {
            int r = (w & 1) * 32 + q32;
            #pragma unroll
            for (int dc = 0; dc < 8; ++dc)
                qf[dc] = *(const bf16x8*)(kbase + r * 256 + ((((dc << 1) | hi) ^ (r & 7)) << 4));
        }
        __syncthreads();
    }

#define STAGE_KV(buf, tile)                                                          \
    for (int i = 0; i < 4; ++i) {                                                    \
        int krow = (t >> 4) + i * 16;                                                \
        __builtin_amdgcn_global_load_lds(                                            \
            (const AS1 uint32_t*)&Kh[(size_t)((tile) * 64 + krow) * 128 + kcc * 8],  \
            kb3 + (buf) * 4096 + (w * 64 + i * 256) * 4, 16, 0, 0);                  \
        int vrow = (t >> 3) + i * 32;                                                \
        __builtin_amdgcn_global_load_lds(                                            \
            (const AS1 uint32_t*)&Vh[(size_t)vrow * 4096 + (tile) * 64 + vcc * 8],   \
            vb3 + (buf) * 4096 + (w * 64 + i * 256) * 4, 16, 0, 0);                  \
    }

    STAGE_KV(0, 0)
    __syncthreads();

    f32x16 oacc[4] = {};
    float rs = 0.0f;
    int cur = 0;

    for (int kb = 0; kb < 64; ++kb) {
        if (kb + 1 < 64) { STAGE_KV(cur ^ 1, kb + 1) }   // async: lands under compute

        const char* ksb = kbase + cur * 16384;
        const char* vsb = vbase + cur * 16384;

        // ---- S^T = K * Q^T - 16.5 (bias via C-init); A-frag = K[k=kt*32+q32][dc*16+hi*8+..] ----
        f32x16 sacc0, sacc1;
        #pragma unroll
        for (int e = 0; e < 16; ++e) { sacc0[e] = -16.5f; sacc1[e] = -16.5f; }
        __builtin_amdgcn_s_setprio(1);
        #pragma unroll
        for (int dc = 0; dc < 8; ++dc) {
            int co = (dc << 1) | hi;
            bf16x8 kf0 = *(const bf16x8*)(ksb + q32 * 256        + ((co ^ (q32 & 7)) << 4));
            bf16x8 kf1 = *(const bf16x8*)(ksb + (32 + q32) * 256 + ((co ^ (q32 & 7)) << 4));
            sacc0 = MFMA32(kf0, qf[dc], sacc0);
            sacc1 = MFMA32(kf1, qf[dc], sacc1);
        }
        __builtin_amdgcn_s_setprio(0);

        // ---- exp2 + in-register P-frags + PV (S^T: lane holds P[q32][(r&3)+8*(r>>2)+4*hi]) ----
        SOFTMAX_PV(sacc0, 0)
        SOFTMAX_PV(sacc1, 1)

        __syncthreads();              // reads of buf[cur] done AND next tile landed
        cur ^= 1;
    }
#undef STAGE_KV

    // ---- epilogue: row-sum (lane + lane^32), broadcast via lred, divide, store ----
    float rt = rs + __shfl_xor(rs, 32);
    if (hi == 0) lred[w][q32] = rt;
    __syncthreads();
    float inv[16];
    #pragma unroll
    for (int r = 0; r < 16; ++r)
        inv[r] = 1.0f / lred[w][(r & 3) + 8 * (r >> 2) + 4 * hi];
    // O layout (32x32 D): col = lane&31 = d, row = (r&3)+8*(r>>2)+4*hi = q_local
    #pragma unroll
    for (int dt = 0; dt < 4; ++dt)
        #pragma unroll
        for (int r = 0; r < 16; ++r) {
            int row = m0 + w * 32 + (r & 3) + 8 * (r >> 2) + 4 * hi;
            int col = h * 128 + dt * 32 + q32;
            ctx[(size_t)row * 2048 + col] = (__bf16)(oacc[dt][r] * inv[r]);
        }
}

// ---------------- launch (5 launches) ----------------
extern "C" void kernel_launch(void* const* d_in, const int* in_sizes, int n_in,
                              void* d_out, int out_size, void* d_ws, size_t ws_size,
                              hipStream_t stream) {
    const float* hs  = (const float*)d_in[0];
    const int*   pos = (const int*)d_in[1];
    const float* wq  = (const float*)d_in[2];
    const float* wk  = (const float*)d_in[3];
    const float* wv  = (const float*)d_in[4];
    const float* wo  = (const float*)d_in[5];
    const float* qw  = (const float*)d_in[6];
    const float* kw  = (const float*)d_in[7];

    char* ws = (char*)d_ws;
    const size_t MB = 1024 * 1024;
    __bf16* xb     = (__bf16*)(ws + 0);
    __bf16* wqkvtb = (__bf16*)(ws + 16 * MB);
    __bf16* qhb    = (__bf16*)(ws + 0);
    __bf16* khb    = (__bf16*)(ws + 16 * MB);
    __bf16* vtb    = (__bf16*)(ws + 32 * MB);
    __bf16* qkvb   = (__bf16*)(ws + 48 * MB);
    __bf16* ctxb   = (__bf16*)(ws + 48 * MB);
    __bf16* wotb   = (__bf16*)(ws + 96 * MB);

    // prep: z<4 weight transposes, z=4 hidden-state convert
    prep<<<dim3(64, 64, 5), dim3(32, 8), 0, stream>>>(hs, wq, wk, wv, wo, xb, wqkvtb, wotb);

    // QKV projection: [4096,2048] x [2048,6144]
    gemm_bt<false><<<dim3(32, 48), 256, 0, stream>>>(xb, 2048, wqkvtb, 2048, qkvb, 6144, 2048);

    // fused rmsrope (y<32) + per-head V transpose (y>=32)
    rope_vt<<<dim3(1024, 40), 256, 0, stream>>>(qkvb, qw, kw, pos, qhb, khb, vtb);

    flash_attn<<<dim3(32, 16), 256, 0, stream>>>(qhb, khb, vtb, ctxb);

    // output projection: [4096,2048] x [2048,2048] -> fp32 out
    gemm_bt<true><<<dim3(32, 16), 256, 0, stream>>>(ctxb, 2048, wotb, 2048, d_out, 2048, 2048);
}

// Round 12
// 472.512 us; speedup vs baseline: 1.0513x; 1.0513x over previous
//
#include <hip/hip_runtime.h>

typedef __bf16 bf16x8 __attribute__((ext_vector_type(8)));
typedef __bf16 bf16x4 __attribute__((ext_vector_type(4)));
typedef float  f32x4  __attribute__((ext_vector_type(4)));
typedef float  f32x16 __attribute__((ext_vector_type(16)));
typedef unsigned u32x4 __attribute__((ext_vector_type(4)));

#define MFMA16(A, B, C) __builtin_amdgcn_mfma_f32_16x16x32_bf16(A, B, C, 0, 0, 0)
#define MFMA32(A, B, C) __builtin_amdgcn_mfma_f32_32x32x16_bf16(A, B, C, 0, 0, 0)
#define AS1 __attribute__((address_space(1)))
#define AS3 __attribute__((address_space(3)))

#if __has_builtin(__builtin_amdgcn_exp2f)
#define EXP2F(x) __builtin_amdgcn_exp2f(x)
#else
#define EXP2F(x) exp2f(x)
#endif

// R12: single-instruction pack (T12 recipe). gfx950 has no scalar bf16 cvt; the previous
// bit_cast version lowered to a multi-inst RNE sequence x16/iter = the bulk of VALUBusy 47%.
__device__ __forceinline__ unsigned pk_bf16(float lo, float hi) {
    unsigned r;
    asm("v_cvt_pk_bf16_f32 %0, %1, %2" : "=v"(r) : "v"(lo), "v"(hi));
    return r;
}

// ---------------- fused prep: 4x weight transpose (fp32 W -> bf16 W^T) + hidden fp32->bf16 ----------------
__global__ __launch_bounds__(256) void prep(const float* __restrict__ hs,
                                            const float* __restrict__ wq,
                                            const float* __restrict__ wk,
                                            const float* __restrict__ wv,
                                            const float* __restrict__ wo,
                                            __bf16* __restrict__ xb,
                                            __bf16* __restrict__ wqkvtb,
                                            __bf16* __restrict__ wotb) {
    __shared__ float tile[32][33];
    const int z = blockIdx.z;
    const int tx = threadIdx.x, ty = threadIdx.y;   // 32x8
    if (z == 4) {                                   // convert: 4096 blocks x 2048 floats
        const int t = ty * 32 + tx;
        size_t bid = (size_t)blockIdx.y * 64 + blockIdx.x;
        size_t base = bid * 2048 + t * 4;
        for (int c = 0; c < 2; ++c) {
            float4 v = *(const float4*)(hs + base + c * 1024);
            bf16x4 o;
            o.x = (__bf16)v.x; o.y = (__bf16)v.y; o.z = (__bf16)v.z; o.w = (__bf16)v.w;
            *(bf16x4*)(xb + base + c * 1024) = o;
        }
        return;
    }
    const float* src = (z == 0) ? wq : (z == 1) ? wk : (z == 2) ? wv : wo;
    __bf16* dst = (z < 3) ? (wqkvtb + (size_t)z * 2048 * 2048) : wotb;
    int x0 = blockIdx.x * 32, y0 = blockIdx.y * 32;
    for (int r = 0; r < 4; ++r)
        tile[ty + 8 * r][tx] = src[(size_t)(y0 + ty + 8 * r) * 2048 + x0 + tx];
    __syncthreads();
    for (int r = 0; r < 4; ++r)
        dst[(size_t)(x0 + ty + 8 * r) * 2048 + y0 + tx] = (__bf16)tile[tx][ty + 8 * r];
}

// ---------------- fused rmsrope + per-head V transpose (both consume qkvb) ----------------
__global__ __launch_bounds__(256) void rope_vt(const __bf16* __restrict__ qkv,
                                               const float* __restrict__ qw,
                                               const float* __restrict__ kw,
                                               const int* __restrict__ pos_ids,
                                               __bf16* __restrict__ qhb,
                                               __bf16* __restrict__ khb,
                                               __bf16* __restrict__ vtb) {
    __shared__ __bf16 tile[32][33];
    if (blockIdx.y < 32) {
        int u = threadIdx.x >> 6, lane = threadIdx.x & 63;
        int s = blockIdx.x * 4 + u;
        int slot = blockIdx.y;              // 0-15 = q heads, 16-31 = k heads
        bool isQ = slot < 16;
        int h = slot & 15;
        size_t base = (size_t)s * 6144 + (isQ ? 0 : 2048) + h * 128 + lane * 2;
        float x0 = (float)qkv[base], x1 = (float)qkv[base + 1];
        float ss = x0 * x0 + x1 * x1;
        for (int m = 1; m < 64; m <<= 1) ss += __shfl_xor(ss, m);
        float rr = rsqrtf(ss * (1.0f / 128.0f) + 1e-6f);
        const float* wp = isQ ? qw : kw;
        float n0 = x0 * rr * wp[lane * 2], n1 = x1 * rr * wp[lane * 2 + 1];
        float freq = EXP2F(-(float)lane * 0.2076205059004571f);   // 10000^(-lane/64)
        float ang = (float)pos_ids[s] * freq;
        float sn, cs;
        sincosf(ang, &sn, &cs);
        float o0 = n0 * cs - n1 * sn;
        float o1 = n0 * sn + n1 * cs;
        // fold (1/sqrt(128)) * log2(e) into Q so scores are in exp2 domain
        if (isQ) { o0 *= 0.12751744416196178f; o1 *= 0.12751744416196178f; }
        __bf16* dst = (isQ ? qhb : khb) + (size_t)h * 4096 * 128 + (size_t)s * 128 + lane * 2;
        dst[0] = (__bf16)o0; dst[1] = (__bf16)o1;
    } else {
        int linear = (blockIdx.y - 32) * 1024 + blockIdx.x;   // [0, 8192)
        int h = linear >> 9, rem = linear & 511;
        int s0 = (rem & 127) * 32, d0 = (rem >> 7) * 32;
        int tx = threadIdx.x & 31, ty = threadIdx.x >> 5;     // 32x8
        for (int r = 0; r < 4; ++r)
            tile[ty + 8 * r][tx] = qkv[(size_t)(s0 + ty + 8 * r) * 6144 + 4096 + h * 128 + d0 + tx];
        __syncthreads();
        for (int r = 0; r < 4; ++r)
            vtb[(size_t)h * 128 * 4096 + (size_t)(d0 + ty + 8 * r) * 4096 + s0 + tx] = tile[tx][ty + 8 * r];
    }
}

// ---------------- generic bf16 MFMA GEMM: C[M,N] = A[M,K] * Bt[N,K]^T ----------------
// R9-proven: 3-deep pipelined K-loop (T3/T4), counted vmcnt, raw s_barriers, 48 KB LDS.
template <bool F32OUT>
__global__ __launch_bounds__(256) void gemm_bt(const __bf16* __restrict__ A, int lda,
                                               const __bf16* __restrict__ Bt, int ldb,
                                               void* __restrict__ Cout, int ldc, int K) {
    __shared__ __bf16 as[3][128][32];   // unpadded: required by global_load_lds contiguity
    __shared__ __bf16 bs[3][128][32];
    const int m0 = blockIdx.x * 128, n0 = blockIdx.y * 128;
    const int t = threadIdx.x;
    const int lane = t & 63, w = t >> 6;
    const int wm = (w >> 1) * 64, wn = (w & 1) * 64;
    const int ln = lane & 15, quad = lane >> 4;
    auto as3 = (AS3 uint32_t*)&as[0][0][0];
    auto bs3 = (AS3 uint32_t*)&bs[0][0][0];
    f32x4 acc[4][4] = {};

#define G_STAGE(buf, k0)                                                             \
    for (int c = 0; c < 2; ++c) {                                                    \
        int g = c * 256 + t;                                                         \
        int row = g >> 2, kc = g & 3;                                                \
        __builtin_amdgcn_global_load_lds(                                            \
            (const AS1 uint32_t*)&A[(size_t)(m0 + row) * lda + (k0) + kc * 8],       \
            as3 + (buf) * 2048 + c * 1024 + w * 256, 16, 0, 0);                      \
        __builtin_amdgcn_global_load_lds(                                            \
            (const AS1 uint32_t*)&Bt[(size_t)(n0 + row) * ldb + (k0) + kc * 8],      \
            bs3 + (buf) * 2048 + c * 1024 + w * 256, 16, 0, 0);                      \
    }

    const int nk = K >> 5;            // K-tiles of 32 (nk >= 2 for all our calls)
    G_STAGE(0, 0)
    G_STAGE(1, 32)
    for (int kt = 0; kt < nk; ++kt) {
        const int nxt = kt + 2;
        if (nxt < nk) {
            G_STAGE(nxt % 3, nxt * 32)
            asm volatile("s_waitcnt vmcnt(8)" ::: "memory");   // tile kt landed; 2 in flight
        } else if (nxt == nk) {
            asm volatile("s_waitcnt vmcnt(4)" ::: "memory");
        } else {
            asm volatile("s_waitcnt vmcnt(0)" ::: "memory");
        }
        __builtin_amdgcn_s_barrier();
        const int b = kt % 3;
        bf16x8 af[4], bfr[4];
        for (int i = 0; i < 4; ++i) af[i] = *(const bf16x8*)&as[b][wm + i * 16 + ln][quad * 8];
        for (int j = 0; j < 4; ++j) bfr[j] = *(const bf16x8*)&bs[b][wn + j * 16 + ln][quad * 8];
        for (int i = 0; i < 4; ++i)
            for (int j = 0; j < 4; ++j)
                acc[i][j] = MFMA16(af[i], bfr[j], acc[i][j]);
        __builtin_amdgcn_s_barrier();   // reads done before anyone re-targets this slot
    }
#undef G_STAGE

    // C/D layout: col = lane&15, row = quad*4 + r   [m89/m91 verified]
    for (int i = 0; i < 4; ++i)
        for (int j = 0; j < 4; ++j)
            for (int r = 0; r < 4; ++r) {
                int row = m0 + wm + i * 16 + quad * 4 + r;
                int col = n0 + wn + j * 16 + ln;
                if (F32OUT) ((float*)Cout)[(size_t)row * ldc + col] = acc[i][j][r];
                else        ((__bf16*)Cout)[(size_t)row * ldc + col] = (__bf16)acc[i][j][r];
            }
}

// ---------------- flash attention: 32x32 MFMA, in-register softmax, gload_lds staging ----------------
// R11-proven structure (164us, WRITE clean). R12 VALU cuts only:
//  (a) pk_bf16 -> inline-asm v_cvt_pk_bf16_f32 (1 inst vs multi-inst RNE sequence x16/iter)
//  (b) persistent mC16 bias vector used as MFMA C-operand for dc=0 (kills 32 movs/iter;
//      MFMA writes D != C so no copy materializes)
// rs stays fp32 (ones-MFMA row-sum rejected: changes denominator rounding vs unknown absmax budget).
#define SOFTMAX_PV(sac, ktv)                                                        \
    {                                                                               \
        float p[16];                                                                \
        _Pragma("unroll")                                                           \
        for (int r = 0; r < 16; ++r) { p[r] = EXP2F((sac)[r]); rs += p[r]; }        \
        unsigned a00 = pk_bf16(p[0], p[1]),  a01 = pk_bf16(p[2], p[3]);             \
        unsigned b00 = pk_bf16(p[4], p[5]),  b01 = pk_bf16(p[6], p[7]);             \
        unsigned a10 = pk_bf16(p[8], p[9]),  a11 = pk_bf16(p[10], p[11]);           \
        unsigned b10 = pk_bf16(p[12], p[13]), b11 = pk_bf16(p[14], p[15]);          \
        auto s00 = __builtin_amdgcn_permlane32_swap(a00, b00, false, false);        \
        auto s01 = __builtin_amdgcn_permlane32_swap(a01, b01, false, false);        \
        auto s10 = __builtin_amdgcn_permlane32_swap(a10, b10, false, false);        \
        auto s11 = __builtin_amdgcn_permlane32_swap(a11, b11, false, false);        \
        u32x4 w0, w1;                                                               \
        w0[0] = s00[0]; w0[1] = s01[0]; w0[2] = s00[1]; w0[3] = s01[1];             \
        w1[0] = s10[0]; w1[1] = s11[0]; w1[2] = s10[1]; w1[3] = s11[1];             \
        bf16x8 pf0 = __builtin_bit_cast(bf16x8, w0);                                \
        bf16x8 pf1 = __builtin_bit_cast(bf16x8, w1);                                \
        __builtin_amdgcn_s_setprio(1);                                              \
        _Pragma("unroll")                                                           \
        for (int dt = 0; dt < 4; ++dt) {                                            \
            int vrow = dt * 32 + q32;                                               \
            int co0 = (((ktv) * 2 + 0) << 1) | hi;                                  \
            int co1 = (((ktv) * 2 + 1) << 1) | hi;                                  \
            bf16x8 vf0 = *(const bf16x8*)(vsb + vrow * 128 + ((co0 ^ (q32 & 7)) << 4)); \
            bf16x8 vf1 = *(const bf16x8*)(vsb + vrow * 128 + ((co1 ^ (q32 & 7)) << 4)); \
            oacc[dt] = MFMA32(pf0, vf0, oacc[dt]);                                  \
            oacc[dt] = MFMA32(pf1, vf1, oacc[dt]);                                  \
        }                                                                           \
        __builtin_amdgcn_s_setprio(0);                                              \
    }

__global__ __launch_bounds__(256) void flash_attn(const __bf16* __restrict__ Q,
                                                  const __bf16* __restrict__ Kb,
                                                  const __bf16* __restrict__ Vt,
                                                  __bf16* __restrict__ ctx) {
    __shared__ __bf16 kbuf[2][64][128];   // keys x dim; phys chunk = logical ^ (row&7)
    __shared__ __bf16 vbuf[2][128][64];   // dim x keys; same involution
    __shared__ float lred[4][32];         // per-wave row-sum broadcast

    // T1: XCD-contiguous remap (verified R1-R11: FETCH 139MB -> 25MB)
    int bid = blockIdx.x + (int)gridDim.x * blockIdx.y;
    int swz = (bid & 7) * 64 + (bid >> 3);
    const int h  = swz >> 5;
    const int m0 = (swz & 31) * 128;

    const int t = threadIdx.x;
    const int lane = t & 63, w = t >> 6;
    const int q32 = lane & 31, hi = lane >> 5;
    const __bf16* Qh = Q + (size_t)h * 4096 * 128;
    const __bf16* Kh = Kb + (size_t)h * 4096 * 128;
    const __bf16* Vh = Vt + (size_t)h * 128 * 4096;

    const int kcc = (t & 15) ^ ((t >> 4) & 7);   // K/Q: 16 chunks/row of 16B
    const int vcc = (t & 7) ^ ((t >> 3) & 7);    // V: 8 chunks/row of 16B
    auto kb3 = (AS3 uint32_t*)&kbuf[0][0][0];
    auto vb3 = (AS3 uint32_t*)&vbuf[0][0][0];
    const char* kbase = (const char*)&kbuf[0][0][0];
    const char* vbase = (const char*)&vbuf[0][0][0];

    // ---- stage Q through kbuf[0]; B-frag: lane holds Q[q=w*32+q32][d = dc*16 + hi*8 + 0..7] ----
    bf16x8 qf[8];
    for (int half = 0; half < 2; ++half) {
        for (int i = 0; i < 4; ++i) {
            int row = (t >> 4) + i * 16;
            *(uint4*)&kbuf[0][row][(t & 15) * 8] =
                *(const uint4*)&Qh[(size_t)(m0 + half * 64 + row) * 128 + kcc * 8];
        }
        __syncthreads();
        if ((w >> 1) == half) {
            int r = (w & 1) * 32 + q32;
            #pragma unroll
            for (int dc = 0; dc < 8; ++dc)
                qf[dc] = *(const bf16x8*)(kbase + r * 256 + ((((dc << 1) | hi) ^ (r & 7)) << 4));
        }
        __syncthreads();
    }

#define STAGE_KV(buf, tile)                                                          \
    for (int i = 0; i < 4; ++i) {                                                    \
        int krow = (t >> 4) + i * 16;                                                \
        __builtin_amdgcn_global_load_lds(                                            \
            (const AS1 uint32_t*)&Kh[(size_t)((tile) * 64 + krow) * 128 + kcc * 8],  \
            kb3 + (buf) * 4096 + (w * 64 + i * 256) * 4, 16, 0, 0);                  \
        int vrow = (t >> 3) + i * 32;                                                \
        __builtin_amdgcn_global_load_lds(                                            \
            (const AS1 uint32_t*)&Vh[(size_t)vrow * 4096 + (tile) * 64 + vcc * 8],   \
            vb3 + (buf) * 4096 + (w * 64 + i * 256) * 4, 16, 0, 0);                  \
    }

    STAGE_KV(0, 0)
    __syncthreads();

    f32x16 oacc[4] = {};
    float rs = 0.0f;
    int cur = 0;

    // persistent bias vector: used as the C-operand of the first QK^T MFMA each tile
    f32x16 mC16;
    #pragma unroll
    for (int e = 0; e < 16; ++e) mC16[e] = -16.5f;

    for (int kb = 0; kb < 64; ++kb) {
        if (kb + 1 < 64) { STAGE_KV(cur ^ 1, kb + 1) }   // async: lands under compute

        const char* ksb = kbase + cur * 16384;
        const char* vsb = vbase + cur * 16384;

        // ---- S^T = K * Q^T - 16.5 (bias via persistent C-operand on dc=0) ----
        f32x16 sacc0, sacc1;
        __builtin_amdgcn_s_setprio(1);
        {
            int co = hi;   // dc = 0
            bf16x8 kf0 = *(const bf16x8*)(ksb + q32 * 256        + ((co ^ (q32 & 7)) << 4));
            bf16x8 kf1 = *(const bf16x8*)(ksb + (32 + q32) * 256 + ((co ^ (q32 & 7)) << 4));
            sacc0 = MFMA32(kf0, qf[0], mC16);
            sacc1 = MFMA32(kf1, qf[0], mC16);
        }
        #pragma unroll
        for (int dc = 1; dc < 8; ++dc) {
            int co = (dc << 1) | hi;
            bf16x8 kf0 = *(const bf16x8*)(ksb + q32 * 256        + ((co ^ (q32 & 7)) << 4));
            bf16x8 kf1 = *(const bf16x8*)(ksb + (32 + q32) * 256 + ((co ^ (q32 & 7)) << 4));
            sacc0 = MFMA32(kf0, qf[dc], sacc0);
            sacc1 = MFMA32(kf1, qf[dc], sacc1);
        }
        __builtin_amdgcn_s_setprio(0);

        // ---- exp2 + in-register P-frags + PV (S^T: lane holds P[q32][(r&3)+8*(r>>2)+4*hi]) ----
        SOFTMAX_PV(sacc0, 0)
        SOFTMAX_PV(sacc1, 1)

        __syncthreads();              // reads of buf[cur] done AND next tile landed
        cur ^= 1;
    }
#undef STAGE_KV

    // ---- epilogue: row-sum (lane + lane^32), broadcast via lred, divide, store ----
    float rt = rs + __shfl_xor(rs, 32);
    if (hi == 0) lred[w][q32] = rt;
    __syncthreads();
    float inv[16];
    #pragma unroll
    for (int r = 0; r < 16; ++r)
        inv[r] = 1.0f / lred[w][(r & 3) + 8 * (r >> 2) + 4 * hi];
    // O layout (32x32 D): col = lane&31 = d, row = (r&3)+8*(r>>2)+4*hi = q_local
    #pragma unroll
    for (int dt = 0; dt < 4; ++dt)
        #pragma unroll
        for (int r = 0; r < 16; ++r) {
            int row = m0 + w * 32 + (r & 3) + 8 * (r >> 2) + 4 * hi;
            int col = h * 128 + dt * 32 + q32;
            ctx[(size_t)row * 2048 + col] = (__bf16)(oacc[dt][r] * inv[r]);
        }
}

// ---------------- launch (5 launches) ----------------
extern "C" void kernel_launch(void* const* d_in, const int* in_sizes, int n_in,
                              void* d_out, int out_size, void* d_ws, size_t ws_size,
                              hipStream_t stream) {
    const float* hs  = (const float*)d_in[0];
    const int*   pos = (const int*)d_in[1];
    const float* wq  = (const float*)d_in[2];
    const float* wk  = (const float*)d_in[3];
    const float* wv  = (const float*)d_in[4];
    const float* wo  = (const float*)d_in[5];
    const float* qw  = (const float*)d_in[6];
    const float* kw  = (const float*)d_in[7];

    char* ws = (char*)d_ws;
    const size_t MB = 1024 * 1024;
    __bf16* xb     = (__bf16*)(ws + 0);
    __bf16* wqkvtb = (__bf16*)(ws + 16 * MB);
    __bf16* qhb    = (__bf16*)(ws + 0);
    __bf16* khb    = (__bf16*)(ws + 16 * MB);
    __bf16* vtb    = (__bf16*)(ws + 32 * MB);
    __bf16* qkvb   = (__bf16*)(ws + 48 * MB);
    __bf16* ctxb   = (__bf16*)(ws + 48 * MB);
    __bf16* wotb   = (__bf16*)(ws + 96 * MB);

    // prep: z<4 weight transposes, z=4 hidden-state convert
    prep<<<dim3(64, 64, 5), dim3(32, 8), 0, stream>>>(hs, wq, wk, wv, wo, xb, wqkvtb, wotb);

    // QKV projection: [4096,2048] x [2048,6144]
    gemm_bt<false><<<dim3(32, 48), 256, 0, stream>>>(xb, 2048, wqkvtb, 2048, qkvb, 6144, 2048);

    // fused rmsrope (y<32) + per-head V transpose (y>=32)
    rope_vt<<<dim3(1024, 40), 256, 0, stream>>>(qkvb, qw, kw, pos, qhb, khb, vtb);

    flash_attn<<<dim3(32, 16), 256, 0, stream>>>(qhb, khb, vtb, ctxb);

    // output projection: [4096,2048] x [2048,2048] -> fp32 out
    gemm_bt<true><<<dim3(32, 16), 256, 0, stream>>>(ctxb, 2048, wotb, 2048, d_out, 2048, 2048);
}

// Round 13
// 450.289 us; speedup vs baseline: 1.1032x; 1.0494x over previous
//
#include <hip/hip_runtime.h>

typedef __bf16 bf16x8 __attribute__((ext_vector_type(8)));
typedef __bf16 bf16x4 __attribute__((ext_vector_type(4)));
typedef float  f32x4  __attribute__((ext_vector_type(4)));
typedef float  f32x16 __attribute__((ext_vector_type(16)));
typedef unsigned u32x4 __attribute__((ext_vector_type(4)));

#define MFMA16(A, B, C) __builtin_amdgcn_mfma_f32_16x16x32_bf16(A, B, C, 0, 0, 0)
#define MFMA32(A, B, C) __builtin_amdgcn_mfma_f32_32x32x16_bf16(A, B, C, 0, 0, 0)
#define AS1 __attribute__((address_space(1)))
#define AS3 __attribute__((address_space(3)))

#if __has_builtin(__builtin_amdgcn_exp2f)
#define EXP2F(x) __builtin_amdgcn_exp2f(x)
#else
#define EXP2F(x) exp2f(x)
#endif

// single-instruction pack (T12 recipe)
__device__ __forceinline__ unsigned pk_bf16(float lo, float hi) {
    unsigned r;
    asm("v_cvt_pk_bf16_f32 %0, %1, %2" : "=v"(r) : "v"(lo), "v"(hi));
    return r;
}

// ---------------- fused prep: 4x weight transpose (fp32 W -> bf16 W^T) + hidden fp32->bf16 ----------------
__global__ __launch_bounds__(256) void prep(const float* __restrict__ hs,
                                            const float* __restrict__ wq,
                                            const float* __restrict__ wk,
                                            const float* __restrict__ wv,
                                            const float* __restrict__ wo,
                                            __bf16* __restrict__ xb,
                                            __bf16* __restrict__ wqkvtb,
                                            __bf16* __restrict__ wotb) {
    __shared__ float tile[32][33];
    const int z = blockIdx.z;
    const int tx = threadIdx.x, ty = threadIdx.y;   // 32x8
    if (z == 4) {                                   // convert: 4096 blocks x 2048 floats
        const int t = ty * 32 + tx;
        size_t bid = (size_t)blockIdx.y * 64 + blockIdx.x;
        size_t base = bid * 2048 + t * 4;
        for (int c = 0; c < 2; ++c) {
            float4 v = *(const float4*)(hs + base + c * 1024);
            bf16x4 o;
            o.x = (__bf16)v.x; o.y = (__bf16)v.y; o.z = (__bf16)v.z; o.w = (__bf16)v.w;
            *(bf16x4*)(xb + base + c * 1024) = o;
        }
        return;
    }
    const float* src = (z == 0) ? wq : (z == 1) ? wk : (z == 2) ? wv : wo;
    __bf16* dst = (z < 3) ? (wqkvtb + (size_t)z * 2048 * 2048) : wotb;
    int x0 = blockIdx.x * 32, y0 = blockIdx.y * 32;
    for (int r = 0; r < 4; ++r)
        tile[ty + 8 * r][tx] = src[(size_t)(y0 + ty + 8 * r) * 2048 + x0 + tx];
    __syncthreads();
    for (int r = 0; r < 4; ++r)
        dst[(size_t)(x0 + ty + 8 * r) * 2048 + y0 + tx] = (__bf16)tile[tx][ty + 8 * r];
}

// ---------------- fused rmsrope + per-head V transpose (both consume qkvb) ----------------
__global__ __launch_bounds__(256) void rope_vt(const __bf16* __restrict__ qkv,
                                               const float* __restrict__ qw,
                                               const float* __restrict__ kw,
                                               const int* __restrict__ pos_ids,
                                               __bf16* __restrict__ qhb,
                                               __bf16* __restrict__ khb,
                                               __bf16* __restrict__ vtb) {
    __shared__ __bf16 tile[32][33];
    if (blockIdx.y < 32) {
        int u = threadIdx.x >> 6, lane = threadIdx.x & 63;
        int s = blockIdx.x * 4 + u;
        int slot = blockIdx.y;              // 0-15 = q heads, 16-31 = k heads
        bool isQ = slot < 16;
        int h = slot & 15;
        size_t base = (size_t)s * 6144 + (isQ ? 0 : 2048) + h * 128 + lane * 2;
        float x0 = (float)qkv[base], x1 = (float)qkv[base + 1];
        float ss = x0 * x0 + x1 * x1;
        for (int m = 1; m < 64; m <<= 1) ss += __shfl_xor(ss, m);
        float rr = rsqrtf(ss * (1.0f / 128.0f) + 1e-6f);
        const float* wp = isQ ? qw : kw;
        float n0 = x0 * rr * wp[lane * 2], n1 = x1 * rr * wp[lane * 2 + 1];
        float freq = EXP2F(-(float)lane * 0.2076205059004571f);   // 10000^(-lane/64)
        float ang = (float)pos_ids[s] * freq;
        float sn, cs;
        sincosf(ang, &sn, &cs);
        float o0 = n0 * cs - n1 * sn;
        float o1 = n0 * sn + n1 * cs;
        // fold (1/sqrt(128)) * log2(e) into Q so scores are in exp2 domain
        if (isQ) { o0 *= 0.12751744416196178f; o1 *= 0.12751744416196178f; }
        __bf16* dst = (isQ ? qhb : khb) + (size_t)h * 4096 * 128 + (size_t)s * 128 + lane * 2;
        dst[0] = (__bf16)o0; dst[1] = (__bf16)o1;
    } else {
        int linear = (blockIdx.y - 32) * 1024 + blockIdx.x;   // [0, 8192)
        int h = linear >> 9, rem = linear & 511;
        int s0 = (rem & 127) * 32, d0 = (rem >> 7) * 32;
        int tx = threadIdx.x & 31, ty = threadIdx.x >> 5;     // 32x8
        for (int r = 0; r < 4; ++r)
            tile[ty + 8 * r][tx] = qkv[(size_t)(s0 + ty + 8 * r) * 6144 + 4096 + h * 128 + d0 + tx];
        __syncthreads();
        for (int r = 0; r < 4; ++r)
            vtb[(size_t)h * 128 * 4096 + (size_t)(d0 + ty + 8 * r) * 4096 + s0 + tx] = tile[tx][ty + 8 * r];
    }
}

// ---------------- generic bf16 MFMA GEMM: C[M,N] = A[M,K] * Bt[N,K]^T ----------------
// R13: BK=64 [128][64] tiles (128B rows) + XOR involution (chunk ^ (row&7)) + 2-buf
// counted-vmcnt(8) 2-deep pipeline.
// WHY: the old [128][32] tiles had 64B rows -> a b128 frag read could only start at 8
// distinct bank positions (bank = 16*(ln&1)+4*quad) = structural 8-way conflict (~2.94x
// on the LDS path, m136; m98 measured 1.7e7 conflicts on this exact tile). 128B rows +
// involution give bank = 4*((ks*4+quad)^(ln&7)) -> all 32 banks, 2 lanes/bank = free.
// Also halves barrier pairs (one per 64-K). Swizzle machinery identical to flash's vbuf
// (R7/R8-proven: linear gload_lds dest + inverse-swizzled per-lane SOURCE + swizzled read).
// MFMA accumulation order unchanged -> bit-identical output.
template <bool F32OUT>
__global__ __launch_bounds__(256) void gemm_bt(const __bf16* __restrict__ A, int lda,
                                               const __bf16* __restrict__ Bt, int ldb,
                                               void* __restrict__ Cout, int ldc, int K) {
    __shared__ __bf16 as[2][128][64];   // 16KB/buf/operand; 64KB total -> 2 blocks/CU
    __shared__ __bf16 bs[2][128][64];
    const int m0 = blockIdx.x * 128, n0 = blockIdx.y * 128;
    const int t = threadIdx.x;
    const int lane = t & 63, w = t >> 6;
    const int wm = (w >> 1) * 64, wn = (w & 1) * 64;
    const int ln = lane & 15, quad = lane >> 4;
    auto as3 = (AS3 uint32_t*)&as[0][0][0];
    auto bs3 = (AS3 uint32_t*)&bs[0][0][0];
    const char* abase = (const char*)&as[0][0][0];
    const char* bbase = (const char*)&bs[0][0][0];
    // per-thread pre-swizzled source chunk (loop-invariant): phys slot t&7 of row holds
    // logical chunk (t&7)^(row&7); row = c*32 + (t>>3) so row&7 = (t>>3)&7 for all c.
    const int scc = (t & 7) ^ ((t >> 3) & 7);
    f32x4 acc[4][4] = {};

    // 8 gload_lds per thread per 64-K tile: A 128x64 (1024 16B-chunks) + B same
#define G_STAGE(buf, k0)                                                             \
    for (int c = 0; c < 4; ++c) {                                                    \
        int g = c * 256 + t;                                                         \
        int row = g >> 3;                                                            \
        __builtin_amdgcn_global_load_lds(                                            \
            (const AS1 uint32_t*)&A[(size_t)(m0 + row) * lda + (k0) + scc * 8],      \
            as3 + (buf) * 4096 + g * 4, 16, 0, 0);                                   \
        __builtin_amdgcn_global_load_lds(                                            \
            (const AS1 uint32_t*)&Bt[(size_t)(n0 + row) * ldb + (k0) + scc * 8],     \
            bs3 + (buf) * 4096 + g * 4, 16, 0, 0);                                   \
    }

    const int nt = K >> 6;            // 64-wide K-tiles (K % 64 == 0 for all our calls)
    G_STAGE(0, 0)
    for (int kt = 0; kt < nt; ++kt) {
        if (kt + 1 < nt) {
            G_STAGE((kt + 1) & 1, (kt + 1) * 64)
            asm volatile("s_waitcnt vmcnt(8)" ::: "memory");   // own tile-kt loads landed; kt+1 in flight
        } else {
            asm volatile("s_waitcnt vmcnt(0)" ::: "memory");   // last tile
        }
        __builtin_amdgcn_s_barrier();
        const char* ab = abase + (kt & 1) * 16384;
        const char* bb = bbase + (kt & 1) * 16384;
        #pragma unroll
        for (int ks = 0; ks < 2; ++ks) {
            bf16x8 af[4], bfr[4];
            #pragma unroll
            for (int i = 0; i < 4; ++i) {
                int rr = wm + i * 16 + ln;
                af[i] = *(const bf16x8*)(ab + rr * 128 + (((ks * 4 + quad) ^ (ln & 7)) << 4));
            }
            #pragma unroll
            for (int j = 0; j < 4; ++j) {
                int rr = wn + j * 16 + ln;
                bfr[j] = *(const bf16x8*)(bb + rr * 128 + (((ks * 4 + quad) ^ (ln & 7)) << 4));
            }
            #pragma unroll
            for (int i = 0; i < 4; ++i)
                #pragma unroll
                for (int j = 0; j < 4; ++j)
                    acc[i][j] = MFMA16(af[i], bfr[j], acc[i][j]);
        }
        __builtin_amdgcn_s_barrier();   // reads of this buffer done before it is re-staged
    }
#undef G_STAGE

    // C/D layout: col = lane&15, row = quad*4 + r   [m89/m91 verified]
    for (int i = 0; i < 4; ++i)
        for (int j = 0; j < 4; ++j)
            for (int r = 0; r < 4; ++r) {
                int row = m0 + wm + i * 16 + quad * 4 + r;
                int col = n0 + wn + j * 16 + ln;
                if (F32OUT) ((float*)Cout)[(size_t)row * ldc + col] = acc[i][j][r];
                else        ((__bf16*)Cout)[(size_t)row * ldc + col] = (__bf16)acc[i][j][r];
            }
}

// ---------------- flash attention: 32x32 MFMA, in-register softmax, gload_lds staging ----------------
// R12-proven: 160us, MfmaUtil 38%, WRITE clean 16.4MB. Parked at ~859 TF (plain-HIP
// 8-warp plateau). Unchanged this round.
#define SOFTMAX_PV(sac, ktv)                                                        \
    {                                                                               \
        float p[16];                                                                \
        _Pragma("unroll")                                                           \
        for (int r = 0; r < 16; ++r) { p[r] = EXP2F((sac)[r]); rs += p[r]; }        \
        unsigned a00 = pk_bf16(p[0], p[1]),  a01 = pk_bf16(p[2], p[3]);             \
        unsigned b00 = pk_bf16(p[4], p[5]),  b01 = pk_bf16(p[6], p[7]);             \
        unsigned a10 = pk_bf16(p[8], p[9]),  a11 = pk_bf16(p[10], p[11]);           \
        unsigned b10 = pk_bf16(p[12], p[13]), b11 = pk_bf16(p[14], p[15]);          \
        auto s00 = __builtin_amdgcn_permlane32_swap(a00, b00, false, false);        \
        auto s01 = __builtin_amdgcn_permlane32_swap(a01, b01, false, false);        \
        auto s10 = __builtin_amdgcn_permlane32_swap(a10, b10, false, false);        \
        auto s11 = __builtin_amdgcn_permlane32_swap(a11, b11, false, false);        \
        u32x4 w0, w1;                                                               \
        w0[0] = s00[0]; w0[1] = s01[0]; w0[2] = s00[1]; w0[3] = s01[1];             \
        w1[0] = s10[0]; w1[1] = s11[0]; w1[2] = s10[1]; w1[3] = s11[1];             \
        bf16x8 pf0 = __builtin_bit_cast(bf16x8, w0);                                \
        bf16x8 pf1 = __builtin_bit_cast(bf16x8, w1);                                \
        __builtin_amdgcn_s_setprio(1);                                              \
        _Pragma("unroll")                                                           \
        for (int dt = 0; dt < 4; ++dt) {                                            \
            int vrow = dt * 32 + q32;                                               \
            int co0 = (((ktv) * 2 + 0) << 1) | hi;                                  \
            int co1 = (((ktv) * 2 + 1) << 1) | hi;                                  \
            bf16x8 vf0 = *(const bf16x8*)(vsb + vrow * 128 + ((co0 ^ (q32 & 7)) << 4)); \
            bf16x8 vf1 = *(const bf16x8*)(vsb + vrow * 128 + ((co1 ^ (q32 & 7)) << 4)); \
            oacc[dt] = MFMA32(pf0, vf0, oacc[dt]);                                  \
            oacc[dt] = MFMA32(pf1, vf1, oacc[dt]);                                  \
        }                                                                           \
        __builtin_amdgcn_s_setprio(0);                                              \
    }

__global__ __launch_bounds__(256) void flash_attn(const __bf16* __restrict__ Q,
                                                  const __bf16* __restrict__ Kb,
                                                  const __bf16* __restrict__ Vt,
                                                  __bf16* __restrict__ ctx) {
    __shared__ __bf16 kbuf[2][64][128];   // keys x dim; phys chunk = logical ^ (row&7)
    __shared__ __bf16 vbuf[2][128][64];   // dim x keys; same involution
    __shared__ float lred[4][32];         // per-wave row-sum broadcast

    // T1: XCD-contiguous remap (verified R1-R12: FETCH 139MB -> 25MB)
    int bid = blockIdx.x + (int)gridDim.x * blockIdx.y;
    int swz = (bid & 7) * 64 + (bid >> 3);
    const int h  = swz >> 5;
    const int m0 = (swz & 31) * 128;

    const int t = threadIdx.x;
    const int lane = t & 63, w = t >> 6;
    const int q32 = lane & 31, hi = lane >> 5;
    const __bf16* Qh = Q + (size_t)h * 4096 * 128;
    const __bf16* Kh = Kb + (size_t)h * 4096 * 128;
    const __bf16* Vh = Vt + (size_t)h * 128 * 4096;

    const int kcc = (t & 15) ^ ((t >> 4) & 7);   // K/Q: 16 chunks/row of 16B
    const int vcc = (t & 7) ^ ((t >> 3) & 7);    // V: 8 chunks/row of 16B
    auto kb3 = (AS3 uint32_t*)&kbuf[0][0][0];
    auto vb3 = (AS3 uint32_t*)&vbuf[0][0][0];
    const char* kbase = (const char*)&kbuf[0][0][0];
    const char* vbase = (const char*)&vbuf[0][0][0];

    // ---- stage Q through kbuf[0]; B-frag: lane holds Q[q=w*32+q32][d = dc*16 + hi*8 + 0..7] ----
    bf16x8 qf[8];
    for (int half = 0; half < 2; ++half) {
        for (int i = 0; i < 4; ++i) {
            int row = (t >> 4) + i * 16;
            *(uint4*)&kbuf[0][row][(t & 15) * 8] =
                *(const uint4*)&Qh[(size_t)(m0 + half * 64 + row) * 128 + kcc * 8];
        }
        __syncthreads();
        if ((w >> 1) == half) {
            int r = (w & 1) * 32 + q32;
            #pragma unroll
            for (int dc = 0; dc < 8; ++dc)
                qf[dc] = *(const bf16x8*)(kbase + r * 256 + ((((dc << 1) | hi) ^ (r & 7)) << 4));
        }
        __syncthreads();
    }

#define STAGE_KV(buf, tile)                                                          \
    for (int i = 0; i < 4; ++i) {                                                    \
        int krow = (t >> 4) + i * 16;                                                \
        __builtin_amdgcn_global_load_lds(                                            \
            (const AS1 uint32_t*)&Kh[(size_t)((tile) * 64 + krow) * 128 + kcc * 8],  \
            kb3 + (buf) * 4096 + (w * 64 + i * 256) * 4, 16, 0, 0);                  \
        int vrow = (t >> 3) + i * 32;                                                \
        __builtin_amdgcn_global_load_lds(                                            \
            (const AS1 uint32_t*)&Vh[(size_t)vrow * 4096 + (tile) * 64 + vcc * 8],   \
            vb3 + (buf) * 4096 + (w * 64 + i * 256) * 4, 16, 0, 0);                  \
    }

    STAGE_KV(0, 0)
    __syncthreads();

    f32x16 oacc[4] = {};
    float rs = 0.0f;
    int cur = 0;

    // persistent bias vector: used as the C-operand of the first QK^T MFMA each tile
    f32x16 mC16;
    #pragma unroll
    for (int e = 0; e < 16; ++e) mC16[e] = -16.5f;

    for (int kb = 0; kb < 64; ++kb) {
        if (kb + 1 < 64) { STAGE_KV(cur ^ 1, kb + 1) }   // async: lands under compute

        const char* ksb = kbase + cur * 16384;
        const char* vsb = vbase + cur * 16384;

        // ---- S^T = K * Q^T - 16.5 (bias via persistent C-operand on dc=0) ----
        f32x16 sacc0, sacc1;
        __builtin_amdgcn_s_setprio(1);
        {
            int co = hi;   // dc = 0
            bf16x8 kf0 = *(const bf16x8*)(ksb + q32 * 256        + ((co ^ (q32 & 7)) << 4));
            bf16x8 kf1 = *(const bf16x8*)(ksb + (32 + q32) * 256 + ((co ^ (q32 & 7)) << 4));
            sacc0 = MFMA32(kf0, qf[0], mC16);
            sacc1 = MFMA32(kf1, qf[0], mC16);
        }
        #pragma unroll
        for (int dc = 1; dc < 8; ++dc) {
            int co = (dc << 1) | hi;
            bf16x8 kf0 = *(const bf16x8*)(ksb + q32 * 256        + ((co ^ (q32 & 7)) << 4));
            bf16x8 kf1 = *(const bf16x8*)(ksb + (32 + q32) * 256 + ((co ^ (q32 & 7)) << 4));
            sacc0 = MFMA32(kf0, qf[dc], sacc0);
            sacc1 = MFMA32(kf1, qf[dc], sacc1);
        }
        __builtin_amdgcn_s_setprio(0);

        // ---- exp2 + in-register P-frags + PV (S^T: lane holds P[q32][(r&3)+8*(r>>2)+4*hi]) ----
        SOFTMAX_PV(sacc0, 0)
        SOFTMAX_PV(sacc1, 1)

        __syncthreads();              // reads of buf[cur] done AND next tile landed
        cur ^= 1;
    }
#undef STAGE_KV

    // ---- epilogue: row-sum (lane + lane^32), broadcast via lred, divide, store ----
    float rt = rs + __shfl_xor(rs, 32);
    if (hi == 0) lred[w][q32] = rt;
    __syncthreads();
    float inv[16];
    #pragma unroll
    for (int r = 0; r < 16; ++r)
        inv[r] = 1.0f / lred[w][(r & 3) + 8 * (r >> 2) + 4 * hi];
    // O layout (32x32 D): col = lane&31 = d, row = (r&3)+8*(r>>2)+4*hi = q_local
    #pragma unroll
    for (int dt = 0; dt < 4; ++dt)
        #pragma unroll
        for (int r = 0; r < 16; ++r) {
            int row = m0 + w * 32 + (r & 3) + 8 * (r >> 2) + 4 * hi;
            int col = h * 128 + dt * 32 + q32;
            ctx[(size_t)row * 2048 + col] = (__bf16)(oacc[dt][r] * inv[r]);
        }
}

// ---------------- launch (5 launches) ----------------
extern "C" void kernel_launch(void* const* d_in, const int* in_sizes, int n_in,
                              void* d_out, int out_size, void* d_ws, size_t ws_size,
                              hipStream_t stream) {
    const float* hs  = (const float*)d_in[0];
    const int*   pos = (const int*)d_in[1];
    const float* wq  = (const float*)d_in[2];
    const float* wk  = (const float*)d_in[3];
    const float* wv  = (const float*)d_in[4];
    const float* wo  = (const float*)d_in[5];
    const float* qw  = (const float*)d_in[6];
    const float* kw  = (const float*)d_in[7];

    char* ws = (char*)d_ws;
    const size_t MB = 1024 * 1024;
    __bf16* xb     = (__bf16*)(ws + 0);
    __bf16* wqkvtb = (__bf16*)(ws + 16 * MB);
    __bf16* qhb    = (__bf16*)(ws + 0);
    __bf16* khb    = (__bf16*)(ws + 16 * MB);
    __bf16* vtb    = (__bf16*)(ws + 32 * MB);
    __bf16* qkvb   = (__bf16*)(ws + 48 * MB);
    __bf16* ctxb   = (__bf16*)(ws + 48 * MB);
    __bf16* wotb   = (__bf16*)(ws + 96 * MB);

    // prep: z<4 weight transposes, z=4 hidden-state convert
    prep<<<dim3(64, 64, 5), dim3(32, 8), 0, stream>>>(hs, wq, wk, wv, wo, xb, wqkvtb, wotb);

    // QKV projection: [4096,2048] x [2048,6144]
    gemm_bt<false><<<dim3(32, 48), 256, 0, stream>>>(xb, 2048, wqkvtb, 2048, qkvb, 6144, 2048);

    // fused rmsrope (y<32) + per-head V transpose (y>=32)
    rope_vt<<<dim3(1024, 40), 256, 0, stream>>>(qkvb, qw, kw, pos, qhb, khb, vtb);

    flash_attn<<<dim3(32, 16), 256, 0, stream>>>(qhb, khb, vtb, ctxb);

    // output projection: [4096,2048] x [2048,2048] -> fp32 out
    gemm_bt<true><<<dim3(32, 16), 256, 0, stream>>>(ctxb, 2048, wotb, 2048, d_out, 2048, 2048);
}